// Round 9
// baseline (1223.869 us; speedup 1.0000x reference)
//
#include <hip/hip_runtime.h>

#define T_STEPS 1000
#define BATCH   256
#define NHID    200
#define ROWF    204      // floats per LDS row (816 B): 200 weights + W2[i] + 3 pad
#define BETA_C  0.85f
#define THR_C   1.0f

// Row i of WT2 holds, at float offset l*4+k (l<50,k<4): Wrec[(l+50k)][i],
// and at offset 200: W2[i]. Lane l does ONE ds_read_b128 per firing neuron i.
// Lane 50's quad starts at float 200 -> .x = W2[i]: its rec0 accumulates cur2
// for free, in ascending firing order.
//
// The ENTIRE sparse gather is one asm volatile block: SALU bit-extraction,
// ds_read_b128 into clobbered v[64:119], counted s_waitcnt lgkmcnt(7), and
// gated v_fmac_f32 accumulation. 7-wide groups, 2 sets (A/B) FIFO, max 14
// DS ops in flight. Gates (0.0f/1.0f in SGPRs) make dummy slots bit-exact
// no-ops; consume order = issue order = ascending neuron index.

// ---- asm string fragments ----
#define RFILL \
    "s_add_i32 s45, s44, 50\n\t" \
    "s_cmp_eq_u64 s[36:37], 0\n\t" \
    "s_cselect_b64 s[36:37], s[38:39], s[36:37]\n\t" \
    "s_cselect_b64 s[38:39], s[40:41], s[38:39]\n\t" \
    "s_cselect_b64 s[40:41], s[42:43], s[40:41]\n\t" \
    "s_cselect_b64 s[42:43], 0, s[42:43]\n\t" \
    "s_cselect_b32 s44, s45, s44\n\t"

#define ORTEST \
    "s_or_b64 s[48:49], s[36:37], s[38:39]\n\t" \
    "s_or_b64 s[48:49], s[48:49], s[40:41]\n\t" \
    "s_or_b64 s[48:49], s[48:49], s[42:43]\n\t" \
    "s_cmp_lg_u64 s[48:49], 0\n\t"

#define SLOT(G, QF, QL) \
    "s_ff1_i32_b64 s46, s[36:37]\n\t" \
    "s_lshl_b64 s[48:49], 1, s46\n\t" \
    "s_andn2_b64 s[36:37], s[36:37], s[48:49]\n\t" \
    "s_add_i32 s47, s46, s44\n\t" \
    "s_mul_i32 s47, s47, 0x330\n\t" \
    "s_cmp_lt_i32 s46, 0\n\t" \
    "s_cselect_b32 " G ", 0, 0x3f800000\n\t" \
    "s_cselect_b32 s47, 0, s47\n\t" \
    "v_add_u32 v60, s47, %[lb]\n\t" \
    "ds_read_b128 v[" QF ":" QL "], v60\n\t"

#define ISSUE_A \
    SLOT("s50","64","67")  SLOT("s51","68","71")  SLOT("s52","72","75") \
    SLOT("s53","76","79")  SLOT("s54","80","83")  SLOT("s55","84","87") \
    SLOT("s56","88","91")

#define ISSUE_B \
    SLOT("s57","92","95")   SLOT("s58","96","99")   SLOT("s59","100","103") \
    SLOT("s60","104","107") SLOT("s61","108","111") SLOT("s62","112","115") \
    SLOT("s63","116","119")

#define CONS(G, A0, A1, A2, A3) \
    "v_fmac_f32 %[r0], " G ", v" A0 "\n\t" \
    "v_fmac_f32 %[r1], " G ", v" A1 "\n\t" \
    "v_fmac_f32 %[r2], " G ", v" A2 "\n\t" \
    "v_fmac_f32 %[r3], " G ", v" A3 "\n\t"

#define CONSUME_A \
    CONS("s50","64","65","66","67")     CONS("s51","68","69","70","71") \
    CONS("s52","72","73","74","75")     CONS("s53","76","77","78","79") \
    CONS("s54","80","81","82","83")     CONS("s55","84","85","86","87") \
    CONS("s56","88","89","90","91")

#define CONSUME_B \
    CONS("s57","92","93","94","95")     CONS("s58","96","97","98","99") \
    CONS("s59","100","101","102","103") CONS("s60","104","105","106","107") \
    CONS("s61","108","109","110","111") CONS("s62","112","113","114","115") \
    CONS("s63","116","117","118","119")

__launch_bounds__(64, 1)
__global__ void rsnn_kernel(const float* __restrict__ X,
                            const float* __restrict__ W1,
                            const float* __restrict__ b1,
                            const float* __restrict__ Wrec,
                            const float* __restrict__ brec,
                            const float* __restrict__ W2,
                            const float* __restrict__ b2,
                            float* __restrict__ out_cur2,
                            float* __restrict__ out_spk) {
#pragma clang fp contract(off)
    __shared__ float WT2[40852];   // 163,408 B

    const int l = threadIdx.x;
    const int b = blockIdx.x;

    // ---- stage Wrec (permuted transpose) + W2 into LDS; zero pads ----
    for (int idx = l; idx < NHID * NHID; idx += 64) {
        int r  = idx / NHID;            // Wrec row  (output neuron)
        int i  = idx - r * NHID;        // Wrec col  (source neuron)
        int lo = r % 50, k = r / 50;
        WT2[i * ROWF + lo * 4 + k] = Wrec[idx];
    }
    for (int i = l; i < NHID; i += 64) {
        WT2[i * ROWF + 200] = W2[i];
        WT2[i * ROWF + 201] = 0.f;
        WT2[i * ROWF + 202] = 0.f;
        WT2[i * ROWF + 203] = 0.f;
    }
    for (int i = 40800 + l; i < 40852; i += 64) WT2[i] = 0.f;
    __syncthreads();

    const int lc = (l < 50) ? l : 49;
    float w1r[4][3], b1r[4], brr[4];
#pragma unroll
    for (int k = 0; k < 4; ++k) {
        int i = lc + 50 * k;
        w1r[k][0] = W1[i * 3 + 0];
        w1r[k][1] = W1[i * 3 + 1];
        w1r[k][2] = W1[i * 3 + 2];
        b1r[k] = b1[i];
        brr[k] = brec[i];
    }
    const float b2v = b2[0];

    float mem0 = 0.f, mem1 = 0.f, mem2 = 0.f, mem3 = 0.f;
    unsigned long long bm0 = 0, bm1 = 0, bm2 = 0, bm3 = 0;

    const float* xp = X + (size_t)b * 3;
    float x0 = xp[0], x1 = xp[1], x2 = xp[2];

    float* spk_base = out_spk + (size_t)b * NHID + lc;

    // 32-bit LDS byte address of this lane's column (generic-pointer low bits
    // are the LDS offset; aperture bases are 2^48-aligned).
    const unsigned lane_byte =
        (unsigned)(unsigned long long)(const void*)WT2 + (unsigned)l * 16u;

    for (int t = 0; t < T_STEPS; ++t) {
        // prefetch next step's input (used one iteration later)
        int   tn  = (t + 1 < T_STEPS) ? t + 1 : t;
        float nx0 = xp[(size_t)tn * BATCH * 3 + 0];
        float nx1 = xp[(size_t)tn * BATCH * 3 + 1];
        float nx2 = xp[(size_t)tn * BATCH * 3 + 2];

        float rec0 = 0.f, rec1 = 0.f, rec2 = 0.f, rec3 = 0.f;

        // ---- full sparse gather in one asm block ----
        asm volatile(
            "s_mov_b64 s[36:37], %[m0]\n\t"
            "s_mov_b64 s[38:39], %[m1]\n\t"
            "s_mov_b64 s[40:41], %[m2]\n\t"
            "s_mov_b64 s[42:43], %[m3]\n\t"
            "s_mov_b32 s44, 0\n\t"
            RFILL
            ISSUE_A
            RFILL
            ISSUE_B
            "GLOOP%=:\n\t"
            "s_waitcnt lgkmcnt(7)\n\t"
            CONSUME_A
            RFILL
            ORTEST
            "s_cbranch_scc0 GEXA%=\n\t"
            ISSUE_A
            "s_waitcnt lgkmcnt(7)\n\t"
            CONSUME_B
            RFILL
            ORTEST
            "s_cbranch_scc0 GEXB%=\n\t"
            ISSUE_B
            "s_branch GLOOP%=\n\t"
            "GEXA%=:\n\t"
            "s_waitcnt lgkmcnt(0)\n\t"
            CONSUME_B
            "s_branch GEND%=\n\t"
            "GEXB%=:\n\t"
            "s_waitcnt lgkmcnt(0)\n\t"
            CONSUME_A
            "GEND%=:\n\t"
            : [r0] "+v"(rec0), [r1] "+v"(rec1), [r2] "+v"(rec2), [r3] "+v"(rec3)
            : [m0] "s"(bm0), [m1] "s"(bm1), [m2] "s"(bm2), [m3] "s"(bm3),
              [lb] "v"(lane_byte)
            : "scc",
              "s36","s37","s38","s39","s40","s41","s42","s43","s44","s45",
              "s46","s47","s48","s49","s50","s51","s52","s53","s54","s55",
              "s56","s57","s58","s59","s60","s61","s62","s63",
              "v60",
              "v64","v65","v66","v67","v68","v69","v70","v71","v72","v73",
              "v74","v75","v76","v77","v78","v79","v80","v81","v82","v83",
              "v84","v85","v86","v87","v88","v89","v90","v91","v92","v93",
              "v94","v95","v96","v97","v98","v99","v100","v101","v102","v103",
              "v104","v105","v106","v107","v108","v109","v110","v111","v112",
              "v113","v114","v115","v116","v117","v118","v119");

        // lane 50's rec0 = sum of W2 over firing set of step t-1 = cur2_{t-1}
        if (t > 0 && l == 50)
            out_cur2[(size_t)(t - 1) * BATCH + b] = rec0 + b2v;

        // ---- membrane update (numpy op/rounding order preserved) ----
        float c0 = fmaf(x2, w1r[0][2], fmaf(x1, w1r[0][1], x0 * w1r[0][0])) + b1r[0];
        float c1 = fmaf(x2, w1r[1][2], fmaf(x1, w1r[1][1], x0 * w1r[1][0])) + b1r[1];
        float c2 = fmaf(x2, w1r[2][2], fmaf(x1, w1r[2][1], x0 * w1r[2][0])) + b1r[2];
        float c3 = fmaf(x2, w1r[3][2], fmaf(x1, w1r[3][1], x0 * w1r[3][0])) + b1r[3];

        float ba0 = ((BETA_C * mem0 + c0) + rec0) + brr[0];
        float ba1 = ((BETA_C * mem1 + c1) + rec1) + brr[1];
        float ba2 = ((BETA_C * mem2 + c2) + rec2) + brr[2];
        float ba3 = ((BETA_C * mem3 + c3) + rec3) + brr[3];

        float nm0 = (mem0 > THR_C) ? 0.f : ba0;
        float nm1 = (mem1 > THR_C) ? 0.f : ba1;
        float nm2 = (mem2 > THR_C) ? 0.f : ba2;
        float nm3 = (mem3 > THR_C) ? 0.f : ba3;

        float sp0 = (nm0 > THR_C) ? 1.f : 0.f;
        float sp1 = (nm1 > THR_C) ? 1.f : 0.f;
        float sp2 = (nm2 > THR_C) ? 1.f : 0.f;
        float sp3 = (nm3 > THR_C) ? 1.f : 0.f;

        mem0 = nm0; mem1 = nm1; mem2 = nm2; mem3 = nm3;

        // ---- record spikes (fire-and-forget coalesced stores, no barrier) ----
        if (l < 50) {
            float* sb = spk_base + (size_t)t * BATCH * NHID;
            sb[0]   = sp0;
            sb[50]  = sp1;
            sb[100] = sp2;
            sb[150] = sp3;
        }

        // ---- publish wave-uniform spike masks for next step ----
        bm0 = __ballot((l < 50) && (sp0 > 0.5f));
        bm1 = __ballot((l < 50) && (sp1 > 0.5f));
        bm2 = __ballot((l < 50) && (sp2 > 0.5f));
        bm3 = __ballot((l < 50) && (sp3 > 0.5f));

        x0 = nx0; x1 = nx1; x2 = nx2;
    }

    // ---- epilogue: cur2_{T-1} from final spike masks (same ascending order) ----
    {
        float c2f = 0.f;
        unsigned long long ms0 = bm0, ms1 = bm1, ms2 = bm2, ms3 = bm3;
#define C2_WORD(M, BASE)                                               \
        {                                                              \
            unsigned long long mm = (M);                               \
            while (mm) {                                               \
                int i = __builtin_ctzll(mm) + (BASE); mm &= mm - 1;    \
                c2f += WT2[i * ROWF + 200];                            \
            }                                                          \
        }
        C2_WORD(ms0, 0) C2_WORD(ms1, 50) C2_WORD(ms2, 100) C2_WORD(ms3, 150)
        if (l == 50)
            out_cur2[(size_t)(T_STEPS - 1) * BATCH + b] = c2f + b2v;
#undef C2_WORD
    }
}

extern "C" void kernel_launch(void* const* d_in, const int* in_sizes, int n_in,
                              void* d_out, int out_size, void* d_ws, size_t ws_size,
                              hipStream_t stream) {
    const float* X    = (const float*)d_in[0];
    const float* W1   = (const float*)d_in[1];
    const float* b1   = (const float*)d_in[2];
    const float* Wrec = (const float*)d_in[3];
    const float* brec = (const float*)d_in[4];
    const float* W2   = (const float*)d_in[5];
    const float* b2   = (const float*)d_in[6];

    float* out_cur2 = (float*)d_out;                            // [T,B,1] flat
    float* out_spk  = (float*)d_out + (size_t)T_STEPS * BATCH;  // [T,B,200] flat

    rsnn_kernel<<<BATCH, 64, 0, stream>>>(X, W1, b1, Wrec, brec, W2, b2,
                                          out_cur2, out_spk);
}

// Round 10
// 841.461 us; speedup vs baseline: 1.4545x; 1.4545x over previous
//
#include <hip/hip_runtime.h>

#define T_STEPS 1000
#define BATCH   256
#define NHID    200
#define ROWF    200      // floats per LDS row (800 B, 16B-aligned)
#define BETA_C  0.85f
#define THR_C   1.0f

// WT2 row i (source neuron i) holds at float offset lo*4+k (lo<50,k<4):
// Wrec[(lo+50k)][i]. Lane lo reads ONE ds_read_b128 per firing source i,
// yielding the 4 weights for its outputs {lo, lo+50, lo+100, lo+150}.
//
// 4 waves per batch element: wave w gathers only source word w (sources
// [50w,50w+50), ~7 firing), writes per-lane float4 partials to LDS, then all
// waves redundantly reduce rec = ((p0+p1)+p2)+p3, update all 200 neurons,
// and ballot all 4 masks (no spike broadcast needed). Splits the serial
// extraction+latency chain 4-way at the cost of two cheap 4-wave barriers.

__launch_bounds__(256, 1)
__global__ void rsnn_kernel(const float* __restrict__ X,
                            const float* __restrict__ W1,
                            const float* __restrict__ b1,
                            const float* __restrict__ Wrec,
                            const float* __restrict__ brec,
                            const float* __restrict__ W2,
                            const float* __restrict__ b2,
                            float* __restrict__ out_cur2,
                            float* __restrict__ out_spk) {
#pragma clang fp contract(off)
    __shared__ float  WT2[NHID * ROWF];   // 160,000 B
    __shared__ float4 part[4][50];        //   3,200 B  -> 163,200 total

    const int tid = threadIdx.x;
    const int l   = tid & 63;            // lane
    const int w   = tid >> 6;            // wave id = source word id
    const int b   = blockIdx.x;

    // ---- stage Wrec (permuted transpose) into LDS ----
    for (int idx = tid; idx < NHID * NHID; idx += 256) {
        int r  = idx / NHID;             // Wrec row  (output neuron)
        int i  = idx - r * NHID;         // Wrec col  (source neuron)
        int lo = r % 50, k = r / 50;
        WT2[i * ROWF + lo * 4 + k] = Wrec[idx];
    }
    __syncthreads();

    const int lc = (l < 50) ? l : 49;    // lanes 50-63 duplicate lane 49
    float w1r[4][3], b1r[4], brr[4], w2r[4];
#pragma unroll
    for (int k = 0; k < 4; ++k) {
        int i = lc + 50 * k;
        w1r[k][0] = W1[i * 3 + 0];
        w1r[k][1] = W1[i * 3 + 1];
        w1r[k][2] = W1[i * 3 + 2];
        b1r[k] = b1[i];
        brr[k] = brec[i];
        w2r[k] = W2[i];
    }
    const float b2v = b2[0];

    float mem0 = 0.f, mem1 = 0.f, mem2 = 0.f, mem3 = 0.f;
    unsigned long long bm0 = 0, bm1 = 0, bm2 = 0, bm3 = 0;

    const float* xp = X + (size_t)b * 3;
    float x0 = xp[0], x1 = xp[1], x2 = xp[2];

    const float* ldsrow = WT2 + (size_t)lc * 4;
    const int    wbase  = 50 * w;

#define REC_WORD(MASK, BASE)                                                          \
    {                                                                                 \
        unsigned long long m = (MASK);                                                \
        while (m) {                                                                   \
            int i0 = __builtin_ctzll(m); m &= m - 1;                                  \
            bool h1 = m != 0; int i1 = h1 ? __builtin_ctzll(m) : i0; if (h1) m &= m - 1; \
            bool h2 = m != 0; int i2 = h2 ? __builtin_ctzll(m) : i0; if (h2) m &= m - 1; \
            bool h3 = m != 0; int i3 = h3 ? __builtin_ctzll(m) : i0; if (h3) m &= m - 1; \
            const float4 v0 = *(const float4*)(ldsrow + (i0 + (BASE)) * ROWF);        \
            const float4 v1 = *(const float4*)(ldsrow + (i1 + (BASE)) * ROWF);        \
            const float4 v2 = *(const float4*)(ldsrow + (i2 + (BASE)) * ROWF);        \
            const float4 v3 = *(const float4*)(ldsrow + (i3 + (BASE)) * ROWF);        \
            pr0 += v0.x; pr1 += v0.y; pr2 += v0.z; pr3 += v0.w;                       \
            if (h1) { pr0 += v1.x; pr1 += v1.y; pr2 += v1.z; pr3 += v1.w; }           \
            if (h2) { pr0 += v2.x; pr1 += v2.y; pr2 += v2.z; pr3 += v2.w; }           \
            if (h3) { pr0 += v3.x; pr1 += v3.y; pr2 += v3.z; pr3 += v3.w; }           \
        }                                                                             \
    }

    for (int t = 0; t < T_STEPS; ++t) {
        // prefetch next step's input (used one iteration later)
        int   tn  = (t + 1 < T_STEPS) ? t + 1 : t;
        float nx0 = xp[(size_t)tn * BATCH * 3 + 0];
        float nx1 = xp[(size_t)tn * BATCH * 3 + 1];
        float nx2 = xp[(size_t)tn * BATCH * 3 + 2];

        // ---- A: gather this wave's source word only (~7 firing) ----
        unsigned long long mw = (w == 0) ? bm0 : (w == 1) ? bm1 : (w == 2) ? bm2 : bm3;
        float pr0 = 0.f, pr1 = 0.f, pr2 = 0.f, pr3 = 0.f;
        REC_WORD(mw, wbase)

        // ---- B: publish per-lane word-partial (16 B/lane) ----
        if (l < 50) part[w][l] = float4{pr0, pr1, pr2, pr3};
        __syncthreads();

        // ---- C: every wave reduces all 4 word-partials (word-blocked order) ----
        const float4 p0 = part[0][lc];
        const float4 p1 = part[1][lc];
        const float4 p2 = part[2][lc];
        const float4 p3 = part[3][lc];
        float rec0 = ((p0.x + p1.x) + p2.x) + p3.x;
        float rec1 = ((p0.y + p1.y) + p2.y) + p3.y;
        float rec2 = ((p0.z + p1.z) + p2.z) + p3.z;
        float rec3 = ((p0.w + p1.w) + p2.w) + p3.w;
        __syncthreads();   // partials consumed; safe to overwrite next step

        // ---- D: membrane update (numpy op/rounding order preserved) ----
        float c0 = fmaf(x2, w1r[0][2], fmaf(x1, w1r[0][1], x0 * w1r[0][0])) + b1r[0];
        float c1 = fmaf(x2, w1r[1][2], fmaf(x1, w1r[1][1], x0 * w1r[1][0])) + b1r[1];
        float c2 = fmaf(x2, w1r[2][2], fmaf(x1, w1r[2][1], x0 * w1r[2][0])) + b1r[2];
        float c3 = fmaf(x2, w1r[3][2], fmaf(x1, w1r[3][1], x0 * w1r[3][0])) + b1r[3];

        float ba0 = ((BETA_C * mem0 + c0) + rec0) + brr[0];
        float ba1 = ((BETA_C * mem1 + c1) + rec1) + brr[1];
        float ba2 = ((BETA_C * mem2 + c2) + rec2) + brr[2];
        float ba3 = ((BETA_C * mem3 + c3) + rec3) + brr[3];

        float nm0 = (mem0 > THR_C) ? 0.f : ba0;
        float nm1 = (mem1 > THR_C) ? 0.f : ba1;
        float nm2 = (mem2 > THR_C) ? 0.f : ba2;
        float nm3 = (mem3 > THR_C) ? 0.f : ba3;

        float sp0 = (nm0 > THR_C) ? 1.f : 0.f;
        float sp1 = (nm1 > THR_C) ? 1.f : 0.f;
        float sp2 = (nm2 > THR_C) ? 1.f : 0.f;
        float sp3 = (nm3 > THR_C) ? 1.f : 0.f;

        mem0 = nm0; mem1 = nm1; mem2 = nm2; mem3 = nm3;

        // ---- E: outputs. wave w stores its 50-spike slice; wave 0 does cur2 ----
        if (l < 50) {
            float spw = (w == 0) ? sp0 : (w == 1) ? sp1 : (w == 2) ? sp2 : sp3;
            out_spk[(size_t)t * BATCH * NHID + (size_t)b * NHID + wbase + l] = spw;
        }
        if (w == 0) {
            // cur2 = sum_j sp_j * W2_j  (terminal output: tree order OK)
            float v = (l < 50)
                ? fmaf(sp3, w2r[3], fmaf(sp2, w2r[2], fmaf(sp1, w2r[1], sp0 * w2r[0])))
                : 0.f;
            for (int o = 32; o >= 1; o >>= 1) v += __shfl_xor(v, o);
            if (l == 0) out_cur2[(size_t)t * BATCH + b] = v + b2v;
        }

        // ---- F: ballots (every wave computes all 4 masks identically) ----
        bm0 = __ballot((l < 50) && (sp0 > 0.5f));
        bm1 = __ballot((l < 50) && (sp1 > 0.5f));
        bm2 = __ballot((l < 50) && (sp2 > 0.5f));
        bm3 = __ballot((l < 50) && (sp3 > 0.5f));

        x0 = nx0; x1 = nx1; x2 = nx2;
    }
#undef REC_WORD
}

extern "C" void kernel_launch(void* const* d_in, const int* in_sizes, int n_in,
                              void* d_out, int out_size, void* d_ws, size_t ws_size,
                              hipStream_t stream) {
    const float* X    = (const float*)d_in[0];
    const float* W1   = (const float*)d_in[1];
    const float* b1   = (const float*)d_in[2];
    const float* Wrec = (const float*)d_in[3];
    const float* brec = (const float*)d_in[4];
    const float* W2   = (const float*)d_in[5];
    const float* b2   = (const float*)d_in[6];

    float* out_cur2 = (float*)d_out;                            // [T,B,1] flat
    float* out_spk  = (float*)d_out + (size_t)T_STEPS * BATCH;  // [T,B,200] flat

    rsnn_kernel<<<BATCH, 256, 0, stream>>>(X, W1, b1, Wrec, brec, W2, b2,
                                           out_cur2, out_spk);
}